// Round 7
// baseline (294.186 us; speedup 1.0000x reference)
//
#include <hip/hip_runtime.h>
#include <hip/hip_bf16.h>

typedef __attribute__((ext_vector_type(4))) float f32x4;
typedef __attribute__((ext_vector_type(8))) __bf16 bf16x8;
typedef __attribute__((ext_vector_type(4))) unsigned int u32x4;

#define EMB 1024
#define NHEAD 16
#define HDIM 64
#define SEQ 2048
#define BATCH 4
#define NTOK 8192

__device__ __forceinline__ unsigned short f2bf(float f) {
    unsigned int u = __builtin_bit_cast(unsigned int, f);
    u = (u + 0x7fffu + ((u >> 16) & 1u)) >> 16;
    return (unsigned short)u;
}

__device__ __forceinline__ unsigned int pack_bf2(float lo, float hi) {
    unsigned int a = __builtin_bit_cast(unsigned int, lo);
    unsigned int b = __builtin_bit_cast(unsigned int, hi);
    return ((a + 0x8000u) >> 16) | ((b + 0x8000u) & 0xffff0000u);
}

__device__ __forceinline__ void async_copy16(const ushort* g, ushort* l) {
    __builtin_amdgcn_global_load_lds(
        (const __attribute__((address_space(1))) void*)g,
        (__attribute__((address_space(3))) void*)l,
        16, 0, 0);
}

// ---------------- fp32 -> bf16 convert ----------------
__global__ void cvt_f32_bf16(const float4* __restrict__ in, ushort* __restrict__ out, int n4) {
    int i = blockIdx.x * 256 + threadIdx.x;
    if (i < n4) {
        float4 v = in[i];
        ushort4 o;
        o.x = f2bf(v.x); o.y = f2bf(v.y); o.z = f2bf(v.z); o.w = f2bf(v.w);
        ((ushort4*)out)[i] = o;
    }
}

// ================= 128x128-tile GEMM core (m97 structure) =================
#define GEMM_STAGE(Asrc, Bsrc, m0, n0, kt)                                        \
    {                                                                             \
        _Pragma("unroll")                                                         \
        for (int j = 0; j < 2; ++j) {                                             \
            int row = wave * 32 + j * 16 + (lane >> 2);                           \
            int kc  = (lane & 3) ^ ((row >> 1) & 3);                              \
            async_copy16(Asrc + (size_t)(m0 + row) * EMB + kt + kc * 8,           \
                         As + (wave * 32 + j * 16) * 32);                         \
            async_copy16(Bsrc + (size_t)(n0 + row) * EMB + kt + kc * 8,           \
                         Bs + (wave * 32 + j * 16) * 32);                         \
        }                                                                         \
    }

#define GEMM_BODY(Asrc, Bsrc, m0, n0)                                             \
    f32x4 acc[4][4] = {};                                                         \
    for (int kt = 0; kt < EMB; kt += 32) {                                        \
        GEMM_STAGE(Asrc, Bsrc, m0, n0, kt)                                        \
        __syncthreads();                                                          \
        bf16x8 a[4], b[4];                                                        \
        _Pragma("unroll")                                                         \
        for (int i = 0; i < 4; ++i) {                                             \
            int r = wm + i * 16 + col;                                            \
            a[i] = *(const bf16x8*)&As[r * 32 + (quad ^ ((r >> 1) & 3)) * 8];     \
            int c = wn + i * 16 + col;                                            \
            b[i] = *(const bf16x8*)&Bs[c * 32 + (quad ^ ((c >> 1) & 3)) * 8];     \
        }                                                                         \
        _Pragma("unroll")                                                         \
        for (int i = 0; i < 4; ++i)                                               \
            _Pragma("unroll")                                                     \
            for (int j = 0; j < 4; ++j)                                           \
                acc[i][j] = __builtin_amdgcn_mfma_f32_16x16x32_bf16(              \
                    a[i], b[j], acc[i][j], 0, 0, 0);                              \
        __syncthreads();                                                          \
    }

// ---------------- QK GEMM: Q prescaled by 1/sqrt(64)*log2(e) in epilogue ----------------
__global__ __launch_bounds__(256) void gemm_qk(
    const ushort* __restrict__ A,
    const ushort* __restrict__ W,
    const float*  __restrict__ bias,
    ushort* __restrict__ Qb, ushort* __restrict__ Kb)
{
    __shared__ ushort As[128 * 32];
    __shared__ ushort Bs[128 * 32];
    const int tid  = threadIdx.x;
    const int lane = tid & 63;
    const int wave = tid >> 6;
    const int col  = lane & 15;
    const int quad = lane >> 4;
    const int m0 = blockIdx.x * 128;
    const int n0 = blockIdx.y * 128;
    const int wm = (wave >> 1) * 64;
    const int wn = (wave & 1) * 64;

    GEMM_BODY(A, W, m0, n0)

    #pragma unroll
    for (int i = 0; i < 4; ++i)
        #pragma unroll
        for (int j = 0; j < 4; ++j)
            #pragma unroll
            for (int r = 0; r < 4; ++r) {
                int m = m0 + wm + i * 16 + quad * 4 + r;
                int n = n0 + wn + j * 16 + col;
                float scl = (n < 1024) ? 0.18033688f : 1.0f;  // SC*log2e folded into Q
                float v = (acc[i][j][r] + bias[n]) * scl;
                unsigned short bv = f2bf(v);
                int e = n & 1023;
                int h = e >> 6, d = e & 63;
                int b = m >> 11, s = m & 2047;
                size_t bh = (size_t)(b * NHEAD + h);
                if (n < 1024) Qb[(bh * SEQ + s) * HDIM + d] = bv;
                else          Kb[(bh * SEQ + s) * HDIM + d] = bv;
            }
}

// ---------------- V^T GEMM: Wv @ X^T -> Vtx[1024,8192] + bias(m) ----------------
__global__ __launch_bounds__(256) void gemm_vt(
    const ushort* __restrict__ Wv,
    const ushort* __restrict__ X,
    const float*  __restrict__ bias,
    ushort* __restrict__ Vtx)
{
    __shared__ ushort As[128 * 32];
    __shared__ ushort Bs[128 * 32];
    const int tid  = threadIdx.x;
    const int lane = tid & 63;
    const int wave = tid >> 6;
    const int col  = lane & 15;
    const int quad = lane >> 4;
    const int m0 = blockIdx.x * 128;   // channel
    const int n0 = blockIdx.y * 128;   // token
    const int wm = (wave >> 1) * 64;
    const int wn = (wave & 1) * 64;

    GEMM_BODY(Wv, X, m0, n0)

    #pragma unroll
    for (int i = 0; i < 4; ++i)
        #pragma unroll
        for (int j = 0; j < 4; ++j)
            #pragma unroll
            for (int r = 0; r < 4; ++r) {
                int m = m0 + wm + i * 16 + quad * 4 + r;
                int n = n0 + wn + j * 16 + col;
                Vtx[(size_t)m * NTOK + n] = f2bf(acc[i][j][r] + bias[m]);
            }
}

// ---------------- Output proj + bias -> fp32 out ----------------
__global__ __launch_bounds__(256) void gemm_proj(
    const ushort* __restrict__ A,
    const ushort* __restrict__ W,
    const float*  __restrict__ bias,
    float* __restrict__ out)
{
    __shared__ ushort As[128 * 32];
    __shared__ ushort Bs[128 * 32];
    const int tid  = threadIdx.x;
    const int lane = tid & 63;
    const int wave = tid >> 6;
    const int col  = lane & 15;
    const int quad = lane >> 4;
    const int m0 = blockIdx.x * 128;
    const int n0 = blockIdx.y * 128;
    const int wm = (wave >> 1) * 64;
    const int wn = (wave & 1) * 64;

    GEMM_BODY(A, W, m0, n0)

    #pragma unroll
    for (int i = 0; i < 4; ++i)
        #pragma unroll
        for (int j = 0; j < 4; ++j)
            #pragma unroll
            for (int r = 0; r < 4; ++r) {
                int m = m0 + wm + i * 16 + quad * 4 + r;
                int n = n0 + wn + j * 16 + col;
                out[(size_t)m * EMB + n] = acc[i][j][r] + bias[n];
            }
}

// ---------------- Flash attention: split-K waves (wave owns 32 keys of the 128-tile) ----------------
// Each wave computes S^T/exp2/P for its 32 keys x ALL 64 q-rows, accumulates partial O^T;
// per-q-tile cross-wave O reduction through LDS scratch (reuses K/V buffers).
// DS reads per tile per wave: 8 (vs 32 for wave=q-split).
__device__ __forceinline__ void attn_qtile(
    int qb, int b, int h, int lane, int wave,
    const ushort* __restrict__ Qh, const ushort* __restrict__ Kh,
    const ushort* __restrict__ Vh, ushort* __restrict__ Yb,
    ushort* __restrict__ Ks0, ushort* __restrict__ Ks1,
    ushort* __restrict__ Vs, float* __restrict__ scratch, float* __restrict__ lrb)
{
    const int col  = lane & 15;
    const int quad = lane >> 4;
    const int q0   = qb * 64;
    const int addr0 = (col + 32 * (quad & 1)) * 4;
    const int addr1 = addr0 + 64;
    const bool hi = quad >= 2;

    // Q fragments for all 4 q-subtiles (Q already prescaled by SC*log2e)
    bf16x8 qf[4][2];
    #pragma unroll
    for (int qs = 0; qs < 4; ++qs) {
        const ushort* qp = Qh + (q0 + qs * 16 + col) * HDIM + quad * 8;
        qf[qs][0] = *(const bf16x8*)(qp);
        qf[qs][1] = *(const bf16x8*)(qp + 32);
    }

    f32x4 o[4][4] = {};      // [dt][qsub], O^T[d=dt*16+quad*4+r][q=qsub*16+col]
    float lr[4] = {};        // per-qsub partial l (q=col)

    const int nk = (qb >> 1) + 1;
    for (int kt = 0; kt < nk; ++kt) {
        const int k0 = kt * 128;
        const bool last = (kt == nk - 1);

        // ---- cooperative staging (same as v6) ----
        {
            int srow = wave * 16 + (lane >> 2);
            #pragma unroll
            for (int rr = 0; rr < 2; ++rr) {
                int r = rr * 64 + srow;
                int kc = (lane & 3) ^ ((r >> 1) & 3);
                const ushort* src = Kh + (size_t)(k0 + r) * HDIM + kc * 8;
                async_copy16(src,      Ks0 + (rr * 64 + wave * 16) * 32);
                async_copy16(src + 32, Ks1 + (rr * 64 + wave * 16) * 32);
            }
            int kc = (lane & 3) ^ ((srow >> 1) & 3);
            const ushort* vsrc = Vh + (size_t)srow * NTOK + k0 + kc * 8;
            #pragma unroll
            for (int kq = 0; kq < 4; ++kq)
                async_copy16(vsrc + kq * 32, Vs + kq * 2048 + (wave * 16) * 32);
        }
        __syncthreads();

        // ---- this wave's K fragments (its 32 keys = j-tiles 2w, 2w+1) ----
        bf16x8 kf0[2], kf1[2];
        #pragma unroll
        for (int j2 = 0; j2 < 2; ++j2) {
            int r = (wave * 2 + j2) * 16 + col;
            int q_ = (quad ^ ((r >> 1) & 3)) * 8;
            kf0[j2] = *(const bf16x8*)&Ks0[r * 32 + q_];
            kf1[j2] = *(const bf16x8*)&Ks1[r * 32 + q_];
        }
        // V fragments for its key-quarter
        bf16x8 vf[4];
        #pragma unroll
        for (int dt = 0; dt < 4; ++dt) {
            int r = dt * 16 + col;
            int q_ = (quad ^ ((r >> 1) & 3)) * 8;
            vf[dt] = *(const bf16x8*)&Vs[wave * 2048 + r * 32 + q_];
        }

        // ---- per q-subtile: S^T, exp2, transpose, PV ----
        #pragma unroll
        for (int qs = 0; qs < 4; ++qs) {
            f32x4 st[2];
            #pragma unroll
            for (int j2 = 0; j2 < 2; ++j2) {
                f32x4 z = {0.f, 0.f, 0.f, 0.f};
                st[j2] = __builtin_amdgcn_mfma_f32_16x16x32_bf16(kf0[j2], qf[qs][0], z, 0, 0, 0);
                st[j2] = __builtin_amdgcn_mfma_f32_16x16x32_bf16(kf1[j2], qf[qs][1], st[j2], 0, 0, 0);
            }
            // p = exp2(st) (scale pre-folded); mask on diagonal tile
            #pragma unroll
            for (int j2 = 0; j2 < 2; ++j2)
                #pragma unroll
                for (int r = 0; r < 4; ++r) {
                    float pv = exp2f(st[j2][r]);
                    if (last) {
                        int c = k0 + (wave * 2 + j2) * 16 + quad * 4 + r;
                        int rowq = q0 + qs * 16 + col;
                        pv = (c <= rowq) ? pv : 0.f;
                    }
                    st[j2][r] = pv;
                    lr[qs] += pv;
                }
            // transpose 32 keys x 16 q -> B-operand fragment (8 bpermute)
            unsigned int pk0[2], pk1[2];
            #pragma unroll
            for (int j2 = 0; j2 < 2; ++j2) {
                pk0[j2] = pack_bf2(st[j2][0], st[j2][1]);
                pk1[j2] = pack_bf2(st[j2][2], st[j2][3]);
            }
            u32x4 ua;
            int b00 = __builtin_amdgcn_ds_bpermute(addr0, (int)pk0[0]);
            int b01 = __builtin_amdgcn_ds_bpermute(addr0, (int)pk1[0]);
            int b02 = __builtin_amdgcn_ds_bpermute(addr1, (int)pk0[0]);
            int b03 = __builtin_amdgcn_ds_bpermute(addr1, (int)pk1[0]);
            int b10 = __builtin_amdgcn_ds_bpermute(addr0, (int)pk0[1]);
            int b11 = __builtin_amdgcn_ds_bpermute(addr0, (int)pk1[1]);
            int b12 = __builtin_amdgcn_ds_bpermute(addr1, (int)pk0[1]);
            int b13 = __builtin_amdgcn_ds_bpermute(addr1, (int)pk1[1]);
            ua[0] = hi ? b10 : b00; ua[1] = hi ? b11 : b01;
            ua[2] = hi ? b12 : b02; ua[3] = hi ? b13 : b03;
            bf16x8 pf = __builtin_bit_cast(bf16x8, ua);

            // partial O^T += V^T @ P^T over this wave's 32 keys
            #pragma unroll
            for (int dt = 0; dt < 4; ++dt)
                o[dt][qs] = __builtin_amdgcn_mfma_f32_16x16x32_bf16(vf[dt], pf, o[dt][qs], 0, 0, 0);
        }
        __syncthreads();
    }

    // ---- cross-wave reduction: l then O in 2 halves through 32KB scratch ----
    #pragma unroll
    for (int qs = 0; qs < 4; ++qs) {
        lr[qs] += __shfl_xor(lr[qs], 16, 64);
        lr[qs] += __shfl_xor(lr[qs], 32, 64);
    }
    if (quad == 0) {
        #pragma unroll
        for (int qs = 0; qs < 4; ++qs)
            lrb[wave * 64 + qs * 16 + col] = lr[qs];
    }
    float linv = 0.f;
    #pragma unroll
    for (int half = 0; half < 2; ++half) {
        // write this wave's partials for dt = 2*half, 2*half+1
        #pragma unroll
        for (int dd = 0; dd < 2; ++dd) {
            int dt = half * 2 + dd;
            #pragma unroll
            for (int qs = 0; qs < 4; ++qs)
                *(f32x4*)&scratch[(((wave * 2 + dd) * 64) + qs * 16 + col) * 16 + quad * 4] = o[dt][qs];
        }
        __syncthreads();
        if (half == 0) {
            float lt = lrb[0 * 64 + wave * 16 + col] + lrb[1 * 64 + wave * 16 + col]
                     + lrb[2 * 64 + wave * 16 + col] + lrb[3 * 64 + wave * 16 + col];
            linv = 1.f / lt;
        }
        // wave owns q-chunk [wave*16, wave*16+16)
        #pragma unroll
        for (int dd = 0; dd < 2; ++dd) {
            int dt = half * 2 + dd;
            f32x4 sum = {0.f, 0.f, 0.f, 0.f};
            #pragma unroll
            for (int sw = 0; sw < 4; ++sw)
                sum += *(const f32x4*)&scratch[(((sw * 2 + dd) * 64) + wave * 16 + col) * 16 + quad * 4];
            int srow = q0 + wave * 16 + col;
            ushort4 s4;
            s4.x = f2bf(sum[0] * linv);
            s4.y = f2bf(sum[1] * linv);
            s4.z = f2bf(sum[2] * linv);
            s4.w = f2bf(sum[3] * linv);
            *(ushort4*)(Yb + ((size_t)(b * SEQ + srow)) * EMB + h * HDIM + dt * 16 + quad * 4) = s4;
        }
        __syncthreads();
    }
}

__global__ __launch_bounds__(256, 2) void attn(
    const ushort* __restrict__ Qb, const ushort* __restrict__ Kb,
    const ushort* __restrict__ Vtx, ushort* __restrict__ Yb)
{
    __shared__ ushort lds_raw[16384 + 512];   // 32KB K/V+scratch union, 1KB lrun
    ushort* Ks0 = lds_raw;
    ushort* Ks1 = lds_raw + 4096;
    ushort* Vs  = lds_raw + 8192;
    float* scratch = (float*)lds_raw;
    float* lrb = (float*)(lds_raw + 16384);

    const int lane = threadIdx.x & 63;
    const int wave = threadIdx.x >> 6;
    const int bh   = blockIdx.x & 63;   // b*16+h
    const int pr   = blockIdx.x >> 6;   // q-tile pair {31-pr, pr}: 17 tile-computes/block

    const int b = bh >> 4, h = bh & 15;
    const ushort* Qh = Qb + (size_t)bh * SEQ * HDIM;
    const ushort* Kh = Kb + (size_t)bh * SEQ * HDIM;
    const ushort* Vh = Vtx + (size_t)(h * HDIM) * NTOK + b * SEQ;

    attn_qtile(31 - pr, b, h, lane, wave, Qh, Kh, Vh, Yb, Ks0, Ks1, Vs, scratch, lrb);
    __syncthreads();
    attn_qtile(pr,      b, h, lane, wave, Qh, Kh, Vh, Yb, Ks0, Ks1, Vs, scratch, lrb);
}

extern "C" void kernel_launch(void* const* d_in, const int* in_sizes, int n_in,
                              void* d_out, int out_size, void* d_ws, size_t ws_size,
                              hipStream_t stream) {
    const float* x      = (const float*)d_in[0];
    const float* W_qkv  = (const float*)d_in[1];
    const float* b_qkv  = (const float*)d_in[2];
    const float* W_proj = (const float*)d_in[3];
    const float* b_proj = (const float*)d_in[4];
    float* out = (float*)d_out;

    ushort* ws     = (ushort*)d_ws;
    ushort* Xb     = ws;                 // reused as Yb after attn inputs ready
    ushort* Yb     = ws;
    ushort* Wqkvb  = ws + 8388608;
    ushort* Wprojb = ws + 11534336;
    ushort* Qb     = ws + 12582912;
    ushort* Kb     = ws + 20971520;
    ushort* Vtx    = ws + 29360128;      // [1024 channels][8192 tokens]

    cvt_f32_bf16<<<8192, 256, 0, stream>>>((const float4*)x,      Xb,     2097152);
    cvt_f32_bf16<<<3072, 256, 0, stream>>>((const float4*)W_qkv,  Wqkvb,  786432);
    cvt_f32_bf16<<<1024, 256, 0, stream>>>((const float4*)W_proj, Wprojb, 262144);

    gemm_qk<<<dim3(64, 16), 256, 0, stream>>>(Xb, Wqkvb, b_qkv, Qb, Kb);
    gemm_vt<<<dim3(8, 64), 256, 0, stream>>>(Wqkvb + (size_t)2048 * EMB, Xb,
                                             b_qkv + 2048, Vtx);
    attn<<<1024, 256, 0, stream>>>(Qb, Kb, Vtx, Yb);
    gemm_proj<<<dim3(64, 8), 256, 0, stream>>>(Yb, Wprojb, b_proj, out);
}